// Round 1
// baseline (87.073 us; speedup 1.0000x reference)
//
#include <hip/hip_runtime.h>
#include <math.h>

// SupConLoss with one-hot embeddings collapses algebraically:
//   mask == 0 everywhere (sim entries are exactly 0/1; the ==1 branch zeroes them)
//   negatives[i] = N;  positive_mask = 1 - diag;  positive_count = N-1
//   loss = N*log(N)/(N-1) - ( sum_c cnt[c]*colsumF[c] - T ) / (TEMP*N*(N-1))
// where colsumF = column sums of features, cnt = column sums of embeddings
// (class counts), T = elementwise dot(features, embeddings) = sum_i feats[i][l_i].
// O(N*D) streaming instead of O(N^2*D).

constexpr int D = 300;
constexpr int F4_PER_ROW = D / 4;       // 75 float4 per row (1200 B, 16B-aligned)
constexpr int TAIL = F4_PER_ROW - 64;   // 11
constexpr int BLOCKS = 256;
constexpr int THREADS = 256;
constexpr int WAVES_PER_BLOCK = THREADS / 64;
constexpr int TOTAL_WAVES = BLOCKS * WAVES_PER_BLOCK;

// ws layout (floats): [0,300) colsumF | [300,600) colsumE (class counts) | [600] T

__global__ __launch_bounds__(THREADS) void supcon_colsums(
    const float* __restrict__ feats, const float* __restrict__ emb,
    float* __restrict__ ws, int n)
{
    __shared__ float sF[D];
    __shared__ float sE[D];
    __shared__ float sT[WAVES_PER_BLOCK];
    const int tid = threadIdx.x;
    for (int i = tid; i < D; i += THREADS) { sF[i] = 0.f; sE[i] = 0.f; }
    if (tid < WAVES_PER_BLOCK) sT[tid] = 0.f;
    __syncthreads();

    const int lane = tid & 63;
    const int wave = tid >> 6;
    const int gw = blockIdx.x * WAVES_PER_BLOCK + wave;  // global wave id

    // one wave reads one row per iteration: lanes 0..63 take float4 0..63,
    // lanes 0..10 additionally take float4 64..74. Register accumulators keep
    // per-lane column partial sums across all of this wave's rows.
    float4 aF0 = make_float4(0.f, 0.f, 0.f, 0.f);
    float4 aE0 = make_float4(0.f, 0.f, 0.f, 0.f);
    float4 aF1 = make_float4(0.f, 0.f, 0.f, 0.f);
    float4 aE1 = make_float4(0.f, 0.f, 0.f, 0.f);
    float tAcc = 0.f;

    for (int r = gw; r < n; r += TOTAL_WAVES) {
        const float4* fr = reinterpret_cast<const float4*>(feats + (size_t)r * D);
        const float4* er = reinterpret_cast<const float4*>(emb + (size_t)r * D);
        float4 f0 = fr[lane];
        float4 e0 = er[lane];
        float4 f1 = make_float4(0.f, 0.f, 0.f, 0.f);
        float4 e1 = make_float4(0.f, 0.f, 0.f, 0.f);
        if (lane < TAIL) { f1 = fr[64 + lane]; e1 = er[64 + lane]; }

        aF0.x += f0.x; aF0.y += f0.y; aF0.z += f0.z; aF0.w += f0.w;
        aE0.x += e0.x; aE0.y += e0.y; aE0.z += e0.z; aE0.w += e0.w;
        aF1.x += f1.x; aF1.y += f1.y; aF1.z += f1.z; aF1.w += f1.w;
        aE1.x += e1.x; aE1.y += e1.y; aE1.z += e1.z; aE1.w += e1.w;
        tAcc += f0.x*e0.x + f0.y*e0.y + f0.z*e0.z + f0.w*e0.w
              + f1.x*e1.x + f1.y*e1.y + f1.z*e1.z + f1.w*e1.w;
    }

    // flush per-lane column accumulators into block LDS (waves collide -> LDS atomics, once per wave)
    {
        const int c0 = lane * 4;
        atomicAdd(&sF[c0 + 0], aF0.x); atomicAdd(&sF[c0 + 1], aF0.y);
        atomicAdd(&sF[c0 + 2], aF0.z); atomicAdd(&sF[c0 + 3], aF0.w);
        atomicAdd(&sE[c0 + 0], aE0.x); atomicAdd(&sE[c0 + 1], aE0.y);
        atomicAdd(&sE[c0 + 2], aE0.z); atomicAdd(&sE[c0 + 3], aE0.w);
        if (lane < TAIL) {
            const int c1 = 256 + lane * 4;
            atomicAdd(&sF[c1 + 0], aF1.x); atomicAdd(&sF[c1 + 1], aF1.y);
            atomicAdd(&sF[c1 + 2], aF1.z); atomicAdd(&sF[c1 + 3], aF1.w);
            atomicAdd(&sE[c1 + 0], aE1.x); atomicAdd(&sE[c1 + 1], aE1.y);
            atomicAdd(&sE[c1 + 2], aE1.z); atomicAdd(&sE[c1 + 3], aE1.w);
        }
    }
    // wave-reduce the dot-product partial
    for (int off = 32; off > 0; off >>= 1) tAcc += __shfl_down(tAcc, off, 64);
    if (lane == 0) sT[wave] = tAcc;
    __syncthreads();

    // one global flush per block (~600 atomics/block, device-scope fp32 fadd)
    for (int i = tid; i < D; i += THREADS) {
        atomicAdd(&ws[i], sF[i]);
        atomicAdd(&ws[D + i], sE[i]);
    }
    if (tid == 0) {
        float t = 0.f;
        for (int w = 0; w < WAVES_PER_BLOCK; ++w) t += sT[w];
        atomicAdd(&ws[2 * D], t);
    }
}

__global__ void supcon_finish(const float* __restrict__ ws,
                              float* __restrict__ out, int n)
{
    const int lane = threadIdx.x;  // launched with 64 threads
    float s = 0.f;
    for (int c = lane; c < D; c += 64) s += ws[c] * ws[D + c];
    for (int off = 32; off > 0; off >>= 1) s += __shfl_down(s, off, 64);
    if (lane == 0) {
        double S = (double)s - (double)ws[2 * D];
        double nd = (double)n;
        double loss = nd * log(nd) / (nd - 1.0) - S / (0.07 * nd * (nd - 1.0));
        out[0] = (float)loss;
    }
}

extern "C" void kernel_launch(void* const* d_in, const int* in_sizes, int n_in,
                              void* d_out, int out_size, void* d_ws, size_t ws_size,
                              hipStream_t stream) {
    const float* feats = (const float*)d_in[0];
    const float* emb   = (const float*)d_in[1];
    float* out = (float*)d_out;
    float* ws  = (float*)d_ws;
    const int n = in_sizes[0] / D;  // 8192

    // ws is re-poisoned to 0xAA before every timed launch -> zero what we use.
    hipMemsetAsync(d_ws, 0, (2 * D + 1) * sizeof(float), stream);
    supcon_colsums<<<BLOCKS, THREADS, 0, stream>>>(feats, emb, ws, n);
    supcon_finish<<<1, 64, 0, stream>>>(ws, out, n);
}